// Round 1
// baseline (2027.737 us; speedup 1.0000x reference)
//
#include <hip/hip_runtime.h>

typedef unsigned int u32;

#define NROWS 500000
#define NCLS  100
#define NBINS 15
#define NRANK 31
#define NSLOT 32

// ---- workspace byte offsets ----
#define OFF_CONF_T 0
#define OFF_CONF_S 2000000
#define OFF_WPER   4000000
#define OFF_CHIST  6000128                 // 65536 u32 coarse hist (top-16 bits)
#define OFF_SMAP   (OFF_CHIST + 262144)    // 65536 int: coarse bin -> slot or -1
#define OFF_SHIST  (OFF_SMAP + 262144)     // 32 * 65536 u32 second-level hists
#define OFF_META   (OFF_SHIST + 8388608)   // ints: [0..30] bin, [32..62] resid, [64..94] slot, [96] nslots
#define OFF_EDGES  (OFF_META + 512)        // 16 doubles
#define OFF_CE     (OFF_EDGES + 128)       // 15 doubles
#define OFF_ACC    (OFF_CE + 128)          // wnum f32[15] @+0, cnt i32[15] @+64, perbin f32[15] @+128
#define OFF_END    (OFF_ACC + 256)

__global__ __launch_bounds__(256) void zero_kernel(u32* __restrict__ p, int n) {
    int i = blockIdx.x * 256 + threadIdx.x;
    if (i < n) p[i] = 0u;
}

// conf = 1/sum(exp(x-max)) == max(softmax(x)); online max+sum, one thread per row.
__global__ __launch_bounds__(256) void conf_target_kernel(
    const float* __restrict__ logits, float* __restrict__ conf, u32* __restrict__ chist)
{
    int r = blockIdx.x * 256 + threadIdx.x;
    if (r >= NROWS) return;
    const float4* rp = (const float4*)(logits + (size_t)r * NCLS);
    float m = -__builtin_inff();
    float s = 0.0f;
    #pragma unroll
    for (int j = 0; j < NCLS / 4; ++j) {
        float4 v = rp[j];
        float cm = v.x;
        if (v.y > cm) cm = v.y;
        if (v.z > cm) cm = v.z;
        if (v.w > cm) cm = v.w;
        if (cm > m) { s *= expf(m - cm); m = cm; }
        s += expf(v.x - m) + expf(v.y - m) + expf(v.z - m) + expf(v.w - m);
    }
    float c = 1.0f / s;
    conf[r] = c;
    atomicAdd(&chist[__float_as_uint(c) >> 16], 1u);
}

__global__ __launch_bounds__(256) void conf_source_kernel(
    const float* __restrict__ logits, const int* __restrict__ labels,
    const float* __restrict__ weight, float* __restrict__ conf, float* __restrict__ wper)
{
    int r = blockIdx.x * 256 + threadIdx.x;
    if (r >= NROWS) return;
    const float4* rp = (const float4*)(logits + (size_t)r * NCLS);
    float m = -__builtin_inff();
    float s = 0.0f;
    int am = 0;
    #pragma unroll
    for (int j = 0; j < NCLS / 4; ++j) {
        float4 v = rp[j];
        float cm = v.x; int ci = 4 * j;
        if (v.y > cm) { cm = v.y; ci = 4 * j + 1; }
        if (v.z > cm) { cm = v.z; ci = 4 * j + 2; }
        if (v.w > cm) { cm = v.w; ci = 4 * j + 3; }
        if (cm > m) { s *= expf(m - cm); m = cm; am = ci; }   // strict > keeps first index (argmax tie-break)
        s += expf(v.x - m) + expf(v.y - m) + expf(v.z - m) + expf(v.w - m);
    }
    conf[r] = 1.0f / s;
    int lab = labels[r];
    wper[r] = (am == lab) ? weight[lab] : 0.0f;
}

// ranks needed: for k=0..14: i_k=floor(k*500000/15) and i_k+1 (q=2k,2k+1); q=30 -> N-1
__device__ __forceinline__ int rank_of(int q) {
    if (q == NRANK - 1) return NROWS - 1;
    int k = q >> 1;
    int ik = (int)(((long long)k * 100000) / 3);   // 500000/15 = 100000/3
    return ik + (q & 1);
}

__global__ __launch_bounds__(256) void rank_prep_kernel(
    const u32* __restrict__ chist, int* __restrict__ smap, int* __restrict__ meta)
{
    __shared__ u32 part[256];
    __shared__ int s_bin[NRANK];
    __shared__ int s_res[NRANK];
    __shared__ int s_slotbin[NSLOT];
    __shared__ int s_ns;
    int t = threadIdx.x;
    u32 csum = 0;
    for (int j = 0; j < 256; ++j) csum += chist[t * 256 + j];
    part[t] = csum;
    __syncthreads();
    if (t == 0) {                 // exclusive scan of 256 partials
        u32 run = 0;
        for (int j = 0; j < 256; ++j) { u32 v = part[j]; part[j] = run; run += v; }
    }
    __syncthreads();
    u32 base = part[t];
    for (int q = 0; q < NRANK; ++q) {      // each rank claimed by exactly one chunk
        u32 r = (u32)rank_of(q);
        if (r >= base && r < base + csum) {
            u32 run = base;
            for (int j = 0; j < 256; ++j) {
                u32 h = chist[t * 256 + j];
                if (r < run + h) { s_bin[q] = t * 256 + j; s_res[q] = (int)(r - run); break; }
                run += h;
            }
        }
    }
    __syncthreads();
    if (t == 0) {                 // dedupe coarse bins -> slots
        int ns = 0;
        for (int q = 0; q < NRANK; ++q) {
            int b = s_bin[q];
            int sl = -1;
            for (int u = 0; u < ns; ++u) if (s_slotbin[u] == b) { sl = u; break; }
            if (sl < 0) { sl = ns; s_slotbin[ns++] = b; }
            meta[q] = b;
            meta[32 + q] = s_res[q];
            meta[64 + q] = sl;
        }
        for (int u = ns; u < NSLOT; ++u) s_slotbin[u] = -1;
        s_ns = ns;
        meta[96] = ns;
    }
    __syncthreads();
    int ns = s_ns;
    for (int idx = t; idx < 65536; idx += 256) {
        int sl = -1;
        for (int u = 0; u < ns; ++u) if (s_slotbin[u] == idx) sl = u;
        smap[idx] = sl;
    }
}

__global__ __launch_bounds__(256) void slot_hist_kernel(
    const float* __restrict__ conf, const int* __restrict__ smap, u32* __restrict__ shist)
{
    int i = blockIdx.x * 256 + threadIdx.x;
    if (i >= NROWS) return;
    u32 b = __float_as_uint(conf[i]);
    int sl = smap[b >> 16];
    if (sl >= 0) atomicAdd(&shist[(size_t)sl * 65536 + (b & 0xFFFFu)], 1u);
}

__global__ __launch_bounds__(256) void select_kernel(
    const u32* __restrict__ shist, const int* __restrict__ meta, double* __restrict__ edges)
{
    __shared__ u32 part[256];
    __shared__ float s_val[NRANK];
    int t = threadIdx.x;
    for (int q = 0; q < NRANK; ++q) {
        int sl = meta[64 + q];
        u32 res = (u32)meta[32 + q];
        int bin = meta[q];
        const u32* h = shist + (size_t)sl * 65536;
        u32 csum = 0;
        for (int j = 0; j < 256; ++j) csum += h[t * 256 + j];
        part[t] = csum;
        __syncthreads();
        if (t == 0) {
            u32 run = 0; int low = 0;
            for (int c = 0; c < 256; ++c) {
                u32 p = part[c];
                if (res < run + p) {
                    u32 r2 = run;
                    for (int j = 0; j < 256; ++j) {
                        u32 hh = h[c * 256 + j];
                        if (res < r2 + hh) { low = c * 256 + j; break; }
                        r2 += hh;
                    }
                    break;
                }
                run += p;
            }
            // bit-exact reconstruction of the order statistic
            s_val[q] = __uint_as_float(((u32)bin << 16) | (u32)low);
        }
        __syncthreads();
    }
    if (t == 0) {
        // replicate np.interp(linspace(0,N,16), arange(N), sorted) in f64
        double step = (double)NROWS / 15.0;
        for (int k = 0; k < 16; ++k) {
            double e;
            if (k == 0)       e = (double)s_val[0];
            else if (k == 15) e = (double)s_val[30];          // xq=N clamps to last element
            else {
                long long ik = ((long long)k * 100000) / 3;
                double xq = (double)k * step;
                double frac = xq - (double)ik;
                double a = (double)s_val[2 * k];
                double b = (double)s_val[2 * k + 1];
                e = a + frac * (b - a);
            }
            edges[k] = e;
        }
    }
}

// bin = (#edges strictly < conf) - 1; valid if in [0,14]. Matches per-bin (>lo)&(<=hi).
__global__ __launch_bounds__(256) void bin_accum_kernel(
    const float* __restrict__ conf_s, const float* __restrict__ wper,
    const float* __restrict__ conf_t, const double* __restrict__ edges,
    float* __restrict__ g_wnum, int* __restrict__ g_cnt)
{
    __shared__ float l_w[NBINS];
    __shared__ int   l_c[NBINS];
    int t = threadIdx.x;
    if (t < NBINS) { l_w[t] = 0.0f; l_c[t] = 0; }
    __syncthreads();
    double e[16];
    #pragma unroll
    for (int j = 0; j < 16; ++j) e[j] = edges[j];
    int i = blockIdx.x * 256 + t;
    if (i < NROWS) {
        double c = (double)conf_s[i];
        int cnt = 0;
        #pragma unroll
        for (int j = 0; j < 16; ++j) cnt += (c > e[j]) ? 1 : 0;
        if (cnt >= 1 && cnt <= NBINS) {
            float w = wper[i];
            if (w != 0.0f) atomicAdd(&l_w[cnt - 1], w);
        }
    } else if (i < 2 * NROWS) {
        double c = (double)conf_t[i - NROWS];
        int cnt = 0;
        #pragma unroll
        for (int j = 0; j < 16; ++j) cnt += (c > e[j]) ? 1 : 0;
        if (cnt >= 1 && cnt <= NBINS) atomicAdd(&l_c[cnt - 1], 1);
    }
    __syncthreads();
    if (t < NBINS) {
        float w = l_w[t];
        int cc = l_c[t];
        if (w != 0.0f) atomicAdd(&g_wnum[t], w);
        if (cc) atomicAdd(&g_cnt[t], cc);
    }
}

__global__ void cond_kernel(const float* __restrict__ g_wnum, const int* __restrict__ g_cnt,
                            double* __restrict__ ce)
{
    int t = threadIdx.x;
    if (t < NBINS) {
        int d = g_cnt[t] - 1; if (d < 1) d = 1;
        ce[t] = ((double)(NROWS - 1) / (double)NROWS) * (double)g_wnum[t] / (double)d;
    }
}

__global__ __launch_bounds__(256) void diff_kernel(
    const float* __restrict__ conf_t, const double* __restrict__ edges,
    const double* __restrict__ ce, float* __restrict__ g_perbin)
{
    __shared__ float l_p[NBINS];
    int t = threadIdx.x;
    if (t < NBINS) l_p[t] = 0.0f;
    __syncthreads();
    double e[16];
    #pragma unroll
    for (int j = 0; j < 16; ++j) e[j] = edges[j];
    int i = blockIdx.x * 256 + t;
    if (i < NROWS) {
        double c = (double)conf_t[i];
        int cnt = 0;
        #pragma unroll
        for (int j = 0; j < 16; ++j) cnt += (c > e[j]) ? 1 : 0;
        if (cnt >= 1 && cnt <= NBINS) {
            double d = c - ce[cnt - 1];
            atomicAdd(&l_p[cnt - 1], (float)(d * d));
        }
    }
    __syncthreads();
    if (t < NBINS) {
        float p = l_p[t];
        if (p != 0.0f) atomicAdd(&g_perbin[t], p);
    }
}

__global__ void final_kernel(const float* __restrict__ g_perbin, const int* __restrict__ g_cnt,
                             float* __restrict__ out)
{
    if (threadIdx.x == 0 && blockIdx.x == 0) {
        double ssum = 0.0;
        for (int b = 0; b < NBINS; ++b)
            if (g_cnt[b] > 1) ssum += (double)g_perbin[b];
        out[0] = (float)(ssum / (double)NROWS);
    }
}

extern "C" void kernel_launch(void* const* d_in, const int* in_sizes, int n_in,
                              void* d_out, int out_size, void* d_ws, size_t ws_size,
                              hipStream_t stream)
{
    const float* logits_s = (const float*)d_in[0];
    const int*   labels   = (const int*)d_in[1];
    const float* logits_t = (const float*)d_in[2];
    const float* weight   = (const float*)d_in[3];

    char* ws = (char*)d_ws;
    float*  conf_t   = (float*)(ws + OFF_CONF_T);
    float*  conf_s   = (float*)(ws + OFF_CONF_S);
    float*  wper     = (float*)(ws + OFF_WPER);
    u32*    chist    = (u32*)(ws + OFF_CHIST);
    int*    smap     = (int*)(ws + OFF_SMAP);
    u32*    shist    = (u32*)(ws + OFF_SHIST);
    int*    meta     = (int*)(ws + OFF_META);
    double* edges    = (double*)(ws + OFF_EDGES);
    double* ce       = (double*)(ws + OFF_CE);
    float*  g_wnum   = (float*)(ws + OFF_ACC);
    int*    g_cnt    = (int*)(ws + OFF_ACC + 64);
    float*  g_perbin = (float*)(ws + OFF_ACC + 128);
    float*  out      = (float*)d_out;

    int zwords = (OFF_END - OFF_CHIST) / 4;
    zero_kernel<<<(zwords + 255) / 256, 256, 0, stream>>>((u32*)(ws + OFF_CHIST), zwords);

    int gb = (NROWS + 255) / 256;
    conf_target_kernel<<<gb, 256, 0, stream>>>(logits_t, conf_t, chist);
    conf_source_kernel<<<gb, 256, 0, stream>>>(logits_s, labels, weight, conf_s, wper);
    rank_prep_kernel<<<1, 256, 0, stream>>>(chist, smap, meta);
    slot_hist_kernel<<<gb, 256, 0, stream>>>(conf_t, smap, shist);
    select_kernel<<<1, 256, 0, stream>>>(shist, meta, edges);
    bin_accum_kernel<<<(2 * NROWS + 255) / 256, 256, 0, stream>>>(conf_s, wper, conf_t, edges, g_wnum, g_cnt);
    cond_kernel<<<1, 64, 0, stream>>>(g_wnum, g_cnt, ce);
    diff_kernel<<<gb, 256, 0, stream>>>(conf_t, edges, ce, g_perbin);
    final_kernel<<<1, 64, 0, stream>>>(g_perbin, g_cnt, out);
}

// Round 2
// 1036.063 us; speedup vs baseline: 1.9572x; 1.9572x over previous
//
#include <hip/hip_runtime.h>
#include <math.h>

typedef unsigned int u32;

#define NROWS 500000
#define NCLS  100
#define NBINS 15
#define NRANK 31
#define NSLOT 32
#define TROWS 64

// ---- workspace byte offsets ----
#define OFF_CONF_T 0
#define OFF_CONF_S 2000000
#define OFF_WPER   4000000
#define OFF_CHIST  6000128                 // 65536 u32 coarse hist (top-16 bits)
#define OFF_SMAP   (OFF_CHIST + 262144)    // 65536 int: coarse bin -> slot or -1
#define OFF_SHIST  (OFF_SMAP + 262144)     // 32 * 65536 u32 second-level hists
#define OFF_META   (OFF_SHIST + 8388608)   // ints: [0..30] bin, [32..62] resid, [64..94] slot, [96] nslots
#define OFF_VALS   (OFF_META + 512)        // 31 floats (order statistics)
#define OFF_EDGES  (OFF_VALS + 128)        // 16 doubles
#define OFF_CE     (OFF_EDGES + 128)       // 15 doubles
#define OFF_ACC    (OFF_CE + 128)          // wnum f32[15] @+0, cnt i32[15] @+64, perbin f32[15] @+128
#define OFF_END    (OFF_ACC + 256)

__global__ __launch_bounds__(256) void zero_kernel(u32* __restrict__ p, int n) {
    int i = blockIdx.x * 256 + threadIdx.x;
    if (i < n) p[i] = 0u;
}

// ---- conf kernels: LDS-tiled, 64 rows/block, 4 lanes per row ----
// merge two online-softmax partials (m,s,am); strict > keeps earlier-index argmax
__device__ __forceinline__ void merge_ms(float& m, float& s, int& am, float m2, float s2, int am2) {
    if (m2 > m) { s = s * expf(m - m2) + s2; m = m2; am = am2; }
    else        { s += s2 * expf(m2 - m); }
}

__device__ __forceinline__ void row_part(const float* rowp, int qd, float& m, float& s, int& am) {
    m = -__builtin_inff(); am = 0;
    #pragma unroll
    for (int i = 0; i < 25; ++i) {
        float v = rowp[i];
        if (v > m) { m = v; am = qd * 25 + i; }
    }
    s = 0.0f;
    #pragma unroll
    for (int i = 0; i < 25; ++i) s += expf(rowp[i] - m);
}

__global__ __launch_bounds__(256) void conf_target_kernel(
    const float* __restrict__ logits, float* __restrict__ conf, u32* __restrict__ chist)
{
    __shared__ float tile[TROWS * NCLS];   // 25.6 KB
    int t = threadIdx.x;
    int tile0 = blockIdx.x * TROWS;
    int rows = NROWS - tile0; if (rows > TROWS) rows = TROWS;
    const float4* gp = (const float4*)(logits + (size_t)tile0 * NCLS);
    int nf4 = rows * 25;
    for (int idx = t; idx < nf4; idx += 256) {
        int r = idx / 25, c = idx % 25;
        *(float4*)&tile[r * NCLS + c * 4] = gp[idx];
    }
    __syncthreads();
    int r = t >> 2, qd = t & 3;
    float m, s; int am;
    row_part(&tile[r * NCLS + qd * 25], qd, m, s, am);
    float m2 = __shfl_down(m, 1); float s2 = __shfl_down(s, 1); int am2 = __shfl_down(am, 1);
    merge_ms(m, s, am, m2, s2, am2);
    m2 = __shfl_down(m, 2); s2 = __shfl_down(s, 2); am2 = __shfl_down(am, 2);
    merge_ms(m, s, am, m2, s2, am2);
    if (qd == 0 && r < rows) {
        float c = 1.0f / s;
        conf[tile0 + r] = c;
        atomicAdd(&chist[__float_as_uint(c) >> 16], 1u);
    }
}

__global__ __launch_bounds__(256) void conf_source_kernel(
    const float* __restrict__ logits, const int* __restrict__ labels,
    const float* __restrict__ weight, float* __restrict__ conf, float* __restrict__ wper)
{
    __shared__ float tile[TROWS * NCLS];
    int t = threadIdx.x;
    int tile0 = blockIdx.x * TROWS;
    int rows = NROWS - tile0; if (rows > TROWS) rows = TROWS;
    const float4* gp = (const float4*)(logits + (size_t)tile0 * NCLS);
    int nf4 = rows * 25;
    for (int idx = t; idx < nf4; idx += 256) {
        int r = idx / 25, c = idx % 25;
        *(float4*)&tile[r * NCLS + c * 4] = gp[idx];
    }
    __syncthreads();
    int r = t >> 2, qd = t & 3;
    float m, s; int am;
    row_part(&tile[r * NCLS + qd * 25], qd, m, s, am);
    float m2 = __shfl_down(m, 1); float s2 = __shfl_down(s, 1); int am2 = __shfl_down(am, 1);
    merge_ms(m, s, am, m2, s2, am2);
    m2 = __shfl_down(m, 2); s2 = __shfl_down(s, 2); am2 = __shfl_down(am, 2);
    merge_ms(m, s, am, m2, s2, am2);
    if (qd == 0 && r < rows) {
        conf[tile0 + r] = 1.0f / s;
        int lab = labels[tile0 + r];
        wper[tile0 + r] = (am == lab) ? weight[lab] : 0.0f;
    }
}

// ranks needed: for k=0..14: i_k=floor(k*500000/15) and i_k+1 (q=2k,2k+1); q=30 -> N-1
__device__ __forceinline__ int rank_of(int q) {
    if (q == NRANK - 1) return NROWS - 1;
    int k = q >> 1;
    int ik = (int)(((long long)k * 100000) / 3);
    return ik + (q & 1);
}

// 1024-thread block: per-thread 64-word chunk sums, block scan via shuffles,
// binary-search locate, cooperative LDS chunk staging, parallel rank walks.
__global__ __launch_bounds__(1024) void rank_prep_kernel(
    const u32* __restrict__ chist, int* __restrict__ smap, int* __restrict__ meta)
{
    __shared__ u32 pre[1024];
    __shared__ u32 wtot[16];
    __shared__ int s_cq[NRANK], s_res[NRANK], s_bin[NRANK];
    __shared__ u32 cd[NRANK * 64];
    __shared__ int s_slotbin[NSLOT];
    __shared__ int s_ns;
    int t = threadIdx.x;
    const uint4* hp = (const uint4*)chist;
    u32 csum = 0;
    for (int j = 0; j < 16; ++j) { uint4 v = hp[t * 16 + j]; csum += v.x + v.y + v.z + v.w; }
    u32 x = csum;
    for (int off = 1; off < 64; off <<= 1) { u32 y = __shfl_up(x, off); if ((t & 63) >= off) x += y; }
    int wv = t >> 6;
    if ((t & 63) == 63) wtot[wv] = x;
    __syncthreads();
    if (t == 0) { u32 run = 0; for (int w = 0; w < 16; ++w) { u32 v = wtot[w]; wtot[w] = run; run += v; } }
    __syncthreads();
    pre[t] = x - csum + wtot[wv];
    __syncthreads();
    if (t < NRANK) {
        u32 r = (u32)rank_of(t);
        int lo = 0, hi = 1023;
        while (lo < hi) { int mid = (lo + hi + 1) >> 1; if (pre[mid] <= r) lo = mid; else hi = mid - 1; }
        s_cq[t] = lo;
        s_res[t] = (int)(r - pre[lo]);
    }
    __syncthreads();
    for (int idx = t; idx < NRANK * 64; idx += 1024) {
        int q = idx >> 6, j = idx & 63;
        cd[idx] = chist[s_cq[q] * 64 + j];
    }
    __syncthreads();
    if (t < NRANK) {
        u32 run = 0; u32 res = (u32)s_res[t]; int bin = 0;
        for (int j = 0; j < 64; ++j) {
            u32 h = cd[t * 64 + j];
            if (res < run + h) { bin = s_cq[t] * 64 + j; s_res[t] = (int)(res - run); break; }
            run += h;
        }
        s_bin[t] = bin;
    }
    __syncthreads();
    if (t == 0) {
        int ns = 0;
        for (int q = 0; q < NRANK; ++q) {
            int b = s_bin[q], sl = -1;
            for (int u = 0; u < ns; ++u) if (s_slotbin[u] == b) { sl = u; break; }
            if (sl < 0) { sl = ns; s_slotbin[ns++] = b; }
            meta[q] = b; meta[32 + q] = s_res[q]; meta[64 + q] = sl;
        }
        s_ns = ns; meta[96] = ns;
        for (int u = ns; u < NSLOT; ++u) s_slotbin[u] = -1;
    }
    __syncthreads();
    int ns = s_ns;
    for (int idx = t; idx < 65536; idx += 1024) {
        int sl = -1;
        for (int u = 0; u < ns; ++u) if (s_slotbin[u] == idx) sl = u;
        smap[idx] = sl;
    }
}

__global__ __launch_bounds__(256) void slot_hist_kernel(
    const float* __restrict__ conf, const int* __restrict__ smap, u32* __restrict__ shist)
{
    int i = blockIdx.x * 256 + threadIdx.x;
    if (i >= NROWS) return;
    u32 b = __float_as_uint(conf[i]);
    int sl = smap[b >> 16];
    if (sl >= 0) atomicAdd(&shist[(size_t)sl * 65536 + (b & 0xFFFFu)], 1u);
}

// one block per rank: block scan over the slot's 65536-bin hist, LDS chunk walk
__global__ __launch_bounds__(1024) void select_kernel(
    const u32* __restrict__ shist, const int* __restrict__ meta, float* __restrict__ vals)
{
    __shared__ u32 wtot[16];
    __shared__ int s_chunk; __shared__ u32 s_base;
    __shared__ u32 cd[64];
    int q = blockIdx.x, t = threadIdx.x;
    int sl = meta[64 + q]; u32 res = (u32)meta[32 + q]; int bin = meta[q];
    const u32* h = shist + (size_t)sl * 65536;
    const uint4* hp = (const uint4*)h;
    u32 csum = 0;
    for (int j = 0; j < 16; ++j) { uint4 v = hp[t * 16 + j]; csum += v.x + v.y + v.z + v.w; }
    u32 x = csum;
    for (int off = 1; off < 64; off <<= 1) { u32 y = __shfl_up(x, off); if ((t & 63) >= off) x += y; }
    int wv = t >> 6;
    if ((t & 63) == 63) wtot[wv] = x;
    __syncthreads();
    if (t == 0) { u32 run = 0; for (int w = 0; w < 16; ++w) { u32 v = wtot[w]; wtot[w] = run; run += v; } }
    __syncthreads();
    u32 prex = x - csum + wtot[wv];
    if (res >= prex && res < prex + csum) { s_chunk = t; s_base = prex; }
    __syncthreads();
    int c = s_chunk;
    if (t < 64) cd[t] = h[c * 64 + t];
    __syncthreads();
    if (t == 0) {
        u32 run = s_base; int low = 0;
        for (int j = 0; j < 64; ++j) {
            u32 hh = cd[j];
            if (res < run + hh) { low = c * 64 + j; break; }
            run += hh;
        }
        vals[q] = __uint_as_float(((u32)bin << 16) | (u32)low);
    }
}

__global__ void edges_kernel(const float* __restrict__ vals, double* __restrict__ edges) {
    if (threadIdx.x == 0 && blockIdx.x == 0) {
        double step = (double)NROWS / 15.0;
        for (int k = 0; k < 16; ++k) {
            double e;
            if (k == 0)       e = (double)vals[0];
            else if (k == 15) e = (double)vals[30];
            else {
                long long ik = ((long long)k * 100000) / 3;
                double frac = (double)k * step - (double)ik;
                double a = (double)vals[2 * k];
                double b = (double)vals[2 * k + 1];
                e = a + frac * (b - a);
            }
            edges[k] = e;
        }
    }
}

// bin = (#edges strictly < conf) - 1; valid if in [0,14].
__global__ __launch_bounds__(256) void bin_accum_kernel(
    const float* __restrict__ conf_s, const float* __restrict__ wper,
    const float* __restrict__ conf_t, const double* __restrict__ edges,
    float* __restrict__ g_wnum, int* __restrict__ g_cnt)
{
    __shared__ float l_w[NBINS];
    __shared__ int   l_c[NBINS];
    int t = threadIdx.x;
    if (t < NBINS) { l_w[t] = 0.0f; l_c[t] = 0; }
    __syncthreads();
    double e[16];
    #pragma unroll
    for (int j = 0; j < 16; ++j) e[j] = edges[j];
    int i = blockIdx.x * 256 + t;
    if (i < NROWS) {
        double c = (double)conf_s[i];
        int cnt = 0;
        #pragma unroll
        for (int j = 0; j < 16; ++j) cnt += (c > e[j]) ? 1 : 0;
        if (cnt >= 1 && cnt <= NBINS) {
            float w = wper[i];
            if (w != 0.0f) atomicAdd(&l_w[cnt - 1], w);
        }
    } else if (i < 2 * NROWS) {
        double c = (double)conf_t[i - NROWS];
        int cnt = 0;
        #pragma unroll
        for (int j = 0; j < 16; ++j) cnt += (c > e[j]) ? 1 : 0;
        if (cnt >= 1 && cnt <= NBINS) atomicAdd(&l_c[cnt - 1], 1);
    }
    __syncthreads();
    if (t < NBINS) {
        float w = l_w[t];
        int cc = l_c[t];
        if (w != 0.0f) atomicAdd(&g_wnum[t], w);
        if (cc) atomicAdd(&g_cnt[t], cc);
    }
}

__global__ void cond_kernel(const float* __restrict__ g_wnum, const int* __restrict__ g_cnt,
                            double* __restrict__ ce)
{
    int t = threadIdx.x;
    if (t < NBINS) {
        int d = g_cnt[t] - 1; if (d < 1) d = 1;
        ce[t] = ((double)(NROWS - 1) / (double)NROWS) * (double)g_wnum[t] / (double)d;
    }
}

__global__ __launch_bounds__(256) void diff_kernel(
    const float* __restrict__ conf_t, const double* __restrict__ edges,
    const double* __restrict__ ce, float* __restrict__ g_perbin)
{
    __shared__ float l_p[NBINS];
    int t = threadIdx.x;
    if (t < NBINS) l_p[t] = 0.0f;
    __syncthreads();
    double e[16];
    #pragma unroll
    for (int j = 0; j < 16; ++j) e[j] = edges[j];
    int i = blockIdx.x * 256 + t;
    if (i < NROWS) {
        double c = (double)conf_t[i];
        int cnt = 0;
        #pragma unroll
        for (int j = 0; j < 16; ++j) cnt += (c > e[j]) ? 1 : 0;
        if (cnt >= 1 && cnt <= NBINS) {
            double d = c - ce[cnt - 1];
            atomicAdd(&l_p[cnt - 1], (float)(d * d));
        }
    }
    __syncthreads();
    if (t < NBINS) {
        float p = l_p[t];
        if (p != 0.0f) atomicAdd(&g_perbin[t], p);
    }
}

__global__ void final_kernel(const float* __restrict__ g_perbin, const int* __restrict__ g_cnt,
                             float* __restrict__ out)
{
    if (threadIdx.x == 0 && blockIdx.x == 0) {
        double ssum = 0.0;
        for (int b = 0; b < NBINS; ++b)
            if (g_cnt[b] > 1) ssum += (double)g_perbin[b];
        out[0] = (float)(ssum / (double)NROWS);
    }
}

extern "C" void kernel_launch(void* const* d_in, const int* in_sizes, int n_in,
                              void* d_out, int out_size, void* d_ws, size_t ws_size,
                              hipStream_t stream)
{
    const float* logits_s = (const float*)d_in[0];
    const int*   labels   = (const int*)d_in[1];
    const float* logits_t = (const float*)d_in[2];
    const float* weight   = (const float*)d_in[3];

    char* ws = (char*)d_ws;
    float*  conf_t   = (float*)(ws + OFF_CONF_T);
    float*  conf_s   = (float*)(ws + OFF_CONF_S);
    float*  wper     = (float*)(ws + OFF_WPER);
    u32*    chist    = (u32*)(ws + OFF_CHIST);
    int*    smap     = (int*)(ws + OFF_SMAP);
    u32*    shist    = (u32*)(ws + OFF_SHIST);
    int*    meta     = (int*)(ws + OFF_META);
    float*  vals     = (float*)(ws + OFF_VALS);
    double* edges    = (double*)(ws + OFF_EDGES);
    double* ce       = (double*)(ws + OFF_CE);
    float*  g_wnum   = (float*)(ws + OFF_ACC);
    int*    g_cnt    = (int*)(ws + OFF_ACC + 64);
    float*  g_perbin = (float*)(ws + OFF_ACC + 128);
    float*  out      = (float*)d_out;

    int zwords = (OFF_END - OFF_CHIST) / 4;
    zero_kernel<<<(zwords + 255) / 256, 256, 0, stream>>>((u32*)(ws + OFF_CHIST), zwords);

    int tb = (NROWS + TROWS - 1) / TROWS;      // 7813 tiles of 64 rows
    int gb = (NROWS + 255) / 256;
    conf_target_kernel<<<tb, 256, 0, stream>>>(logits_t, conf_t, chist);
    conf_source_kernel<<<tb, 256, 0, stream>>>(logits_s, labels, weight, conf_s, wper);
    rank_prep_kernel<<<1, 1024, 0, stream>>>(chist, smap, meta);
    slot_hist_kernel<<<gb, 256, 0, stream>>>(conf_t, smap, shist);
    select_kernel<<<NRANK, 1024, 0, stream>>>(shist, meta, vals);
    edges_kernel<<<1, 64, 0, stream>>>(vals, edges);
    bin_accum_kernel<<<(2 * NROWS + 255) / 256, 256, 0, stream>>>(conf_s, wper, conf_t, edges, g_wnum, g_cnt);
    cond_kernel<<<1, 64, 0, stream>>>(g_wnum, g_cnt, ce);
    diff_kernel<<<gb, 256, 0, stream>>>(conf_t, edges, ce, g_perbin);
    final_kernel<<<1, 64, 0, stream>>>(g_perbin, g_cnt, out);
}

// Round 3
// 566.385 us; speedup vs baseline: 3.5801x; 1.8293x over previous
//
#include <hip/hip_runtime.h>
#include <math.h>

typedef unsigned int u32;

#define NROWS 500000
#define NCLS  100
#define NBINS 15
#define NRANK 31
#define NSLOT 32
#define TROWS 64
#define HISTB 128

// ---- workspace byte offsets ----
#define OFF_CONF_T 0
#define OFF_CONF_S 2000000
#define OFF_WPER   4000000
// zeroed span: [OFF_CHIST, OFF_ZEND)
#define OFF_CHIST  6000128                 // 65536 u32 coarse hist (top-16 bits of conf)
#define OFF_SHIST  (OFF_CHIST + 262144)    // 32 * 65536 u32 second-level hists
#define OFF_ACC    (OFF_SHIST + 8388608)   // wnum f32[15] @+0, cnt i32[15] @+64, perbin f32[15] @+128
#define OFF_ZEND   (OFF_ACC + 256)
// not zeroed (fully overwritten):
#define OFF_SMAP   OFF_ZEND                // 65536 int: coarse bin -> slot or -1
#define OFF_META   (OFF_SMAP + 262144)     // ints: [0..30] bin, [32..62] resid, [64..94] slot, [96] nslots
#define OFF_VALS   (OFF_META + 512)        // 31 floats (order statistics)
#define OFF_EDGES  (OFF_VALS + 128)        // 16 doubles
#define OFF_CE     (OFF_EDGES + 128)       // 15 doubles

__global__ __launch_bounds__(256) void zero_kernel(u32* __restrict__ p, int n) {
    int i = blockIdx.x * 256 + threadIdx.x;
    if (i < n) p[i] = 0u;
}

// ---- merged conf kernel: LDS-tiled, 64 rows/block, 4 lanes per row ----
// merge two online-softmax partials (m,s,am); strict > keeps earlier-index argmax
__device__ __forceinline__ void merge_ms(float& m, float& s, int& am, float m2, float s2, int am2) {
    if (m2 > m) { s = s * expf(m - m2) + s2; m = m2; am = am2; }
    else        { s += s2 * expf(m2 - m); }
}

__device__ __forceinline__ void row_part(const float* rowp, int qd, float& m, float& s, int& am) {
    m = -__builtin_inff(); am = 0;
    #pragma unroll
    for (int i = 0; i < 25; ++i) {
        float v = rowp[i];
        if (v > m) { m = v; am = qd * 25 + i; }
    }
    s = 0.0f;
    #pragma unroll
    for (int i = 0; i < 25; ++i) s += expf(rowp[i] - m);
}

// blockIdx < tb: target rows (conf only). blockIdx >= tb: source rows (conf + wper).
__global__ __launch_bounds__(256) void conf_kernel(
    const float* __restrict__ logits_t, const float* __restrict__ logits_s,
    const int* __restrict__ labels, const float* __restrict__ weight,
    float* __restrict__ conf_t, float* __restrict__ conf_s,
    float* __restrict__ wper, int tb)
{
    __shared__ float tile[TROWS * NCLS];   // 25.6 KB
    int t = threadIdx.x;
    bool is_src = (int)blockIdx.x >= tb;
    int bid = is_src ? (int)blockIdx.x - tb : (int)blockIdx.x;
    const float* logits = is_src ? logits_s : logits_t;
    int tile0 = bid * TROWS;
    int rows = NROWS - tile0; if (rows > TROWS) rows = TROWS;
    const float4* gp = (const float4*)(logits + (size_t)tile0 * NCLS);
    int nf4 = rows * 25;
    for (int idx = t; idx < nf4; idx += 256) {
        int r = idx / 25, c = idx % 25;
        *(float4*)&tile[r * NCLS + c * 4] = gp[idx];
    }
    __syncthreads();
    int r = t >> 2, qd = t & 3;
    float m, s; int am;
    row_part(&tile[r * NCLS + qd * 25], qd, m, s, am);
    float m2 = __shfl_down(m, 1); float s2 = __shfl_down(s, 1); int am2 = __shfl_down(am, 1);
    merge_ms(m, s, am, m2, s2, am2);
    m2 = __shfl_down(m, 2); s2 = __shfl_down(s, 2); am2 = __shfl_down(am, 2);
    merge_ms(m, s, am, m2, s2, am2);
    if (qd == 0 && r < rows) {
        float c = 1.0f / s;
        if (is_src) {
            conf_s[tile0 + r] = c;
            int lab = labels[tile0 + r];
            wper[tile0 + r] = (am == lab) ? weight[lab] : 0.0f;
        } else {
            conf_t[tile0 + r] = c;
        }
    }
}

// coarse histogram of conf_t top-16 bits with LDS privatization.
// conf in (1/NCLS, 1] -> code in [15395, 16256]; LDS covers [15360, 16384).
__global__ __launch_bounds__(256) void hist_kernel(
    const float* __restrict__ conf, u32* __restrict__ chist)
{
    __shared__ u32 h[1024];
    int t = threadIdx.x;
    for (int i = t; i < 1024; i += 256) h[i] = 0u;
    __syncthreads();
    for (int i = blockIdx.x * 256 + t; i < NROWS; i += HISTB * 256) {
        u32 b = __float_as_uint(conf[i]) >> 16;
        u32 u = b - 15360u;
        if (u < 1024u) atomicAdd(&h[u], 1u);
        else atomicAdd(&chist[b], 1u);   // safety net; mathematically unreachable
    }
    __syncthreads();
    for (int i = t; i < 1024; i += 256) {
        u32 v = h[i];
        if (v) atomicAdd(&chist[15360 + i], v);
    }
}

// ranks needed: for k=0..14: i_k=floor(k*500000/15) and i_k+1 (q=2k,2k+1); q=30 -> N-1
__device__ __forceinline__ int rank_of(int q) {
    if (q == NRANK - 1) return NROWS - 1;
    int k = q >> 1;
    int ik = (int)(((long long)k * 100000) / 3);
    return ik + (q & 1);
}

// 1024-thread block: per-thread 64-word chunk sums, block scan via shuffles,
// binary-search locate, cooperative LDS chunk staging, parallel rank walks.
__global__ __launch_bounds__(1024) void rank_prep_kernel(
    const u32* __restrict__ chist, int* __restrict__ smap, int* __restrict__ meta)
{
    __shared__ u32 pre[1024];
    __shared__ u32 wtot[16];
    __shared__ int s_cq[NRANK], s_res[NRANK], s_bin[NRANK];
    __shared__ u32 cd[NRANK * 64];
    __shared__ int s_slotbin[NSLOT];
    __shared__ int s_ns;
    int t = threadIdx.x;
    const uint4* hp = (const uint4*)chist;
    u32 csum = 0;
    for (int j = 0; j < 16; ++j) { uint4 v = hp[t * 16 + j]; csum += v.x + v.y + v.z + v.w; }
    u32 x = csum;
    for (int off = 1; off < 64; off <<= 1) { u32 y = __shfl_up(x, off); if ((t & 63) >= off) x += y; }
    int wv = t >> 6;
    if ((t & 63) == 63) wtot[wv] = x;
    __syncthreads();
    if (t == 0) { u32 run = 0; for (int w = 0; w < 16; ++w) { u32 v = wtot[w]; wtot[w] = run; run += v; } }
    __syncthreads();
    pre[t] = x - csum + wtot[wv];
    __syncthreads();
    if (t < NRANK) {
        u32 r = (u32)rank_of(t);
        int lo = 0, hi = 1023;
        while (lo < hi) { int mid = (lo + hi + 1) >> 1; if (pre[mid] <= r) lo = mid; else hi = mid - 1; }
        s_cq[t] = lo;
        s_res[t] = (int)(r - pre[lo]);
    }
    __syncthreads();
    for (int idx = t; idx < NRANK * 64; idx += 1024) {
        int q = idx >> 6, j = idx & 63;
        cd[idx] = chist[s_cq[q] * 64 + j];
    }
    __syncthreads();
    if (t < NRANK) {
        u32 run = 0; u32 res = (u32)s_res[t]; int bin = 0;
        for (int j = 0; j < 64; ++j) {
            u32 h = cd[t * 64 + j];
            if (res < run + h) { bin = s_cq[t] * 64 + j; s_res[t] = (int)(res - run); break; }
            run += h;
        }
        s_bin[t] = bin;
    }
    __syncthreads();
    if (t == 0) {
        int ns = 0;
        for (int q = 0; q < NRANK; ++q) {
            int b = s_bin[q], sl = -1;
            for (int u = 0; u < ns; ++u) if (s_slotbin[u] == b) { sl = u; break; }
            if (sl < 0) { sl = ns; s_slotbin[ns++] = b; }
            meta[q] = b; meta[32 + q] = s_res[q]; meta[64 + q] = sl;
        }
        s_ns = ns; meta[96] = ns;
        for (int u = ns; u < NSLOT; ++u) s_slotbin[u] = -1;
    }
    __syncthreads();
    int ns = s_ns;
    for (int idx = t; idx < 65536; idx += 1024) {
        int sl = -1;
        for (int u = 0; u < ns; ++u) if (s_slotbin[u] == idx) sl = u;
        smap[idx] = sl;
    }
}

__global__ __launch_bounds__(256) void slot_hist_kernel(
    const float* __restrict__ conf, const int* __restrict__ smap, u32* __restrict__ shist)
{
    int i = blockIdx.x * 256 + threadIdx.x;
    if (i >= NROWS) return;
    u32 b = __float_as_uint(conf[i]);
    int sl = smap[b >> 16];
    if (sl >= 0) atomicAdd(&shist[(size_t)sl * 65536 + (b & 0xFFFFu)], 1u);
}

// one block per rank: block scan over the slot's 65536-bin hist, LDS chunk walk
__global__ __launch_bounds__(1024) void select_kernel(
    const u32* __restrict__ shist, const int* __restrict__ meta, float* __restrict__ vals)
{
    __shared__ u32 wtot[16];
    __shared__ int s_chunk; __shared__ u32 s_base;
    __shared__ u32 cd[64];
    int q = blockIdx.x, t = threadIdx.x;
    int sl = meta[64 + q]; u32 res = (u32)meta[32 + q]; int bin = meta[q];
    const u32* h = shist + (size_t)sl * 65536;
    const uint4* hp = (const uint4*)h;
    u32 csum = 0;
    for (int j = 0; j < 16; ++j) { uint4 v = hp[t * 16 + j]; csum += v.x + v.y + v.z + v.w; }
    u32 x = csum;
    for (int off = 1; off < 64; off <<= 1) { u32 y = __shfl_up(x, off); if ((t & 63) >= off) x += y; }
    int wv = t >> 6;
    if ((t & 63) == 63) wtot[wv] = x;
    __syncthreads();
    if (t == 0) { u32 run = 0; for (int w = 0; w < 16; ++w) { u32 v = wtot[w]; wtot[w] = run; run += v; } }
    __syncthreads();
    u32 prex = x - csum + wtot[wv];
    if (res >= prex && res < prex + csum) { s_chunk = t; s_base = prex; }
    __syncthreads();
    int c = s_chunk;
    if (t < 64) cd[t] = h[c * 64 + t];
    __syncthreads();
    if (t == 0) {
        u32 run = s_base; int low = 0;
        for (int j = 0; j < 64; ++j) {
            u32 hh = cd[j];
            if (res < run + hh) { low = c * 64 + j; break; }
            run += hh;
        }
        vals[q] = __uint_as_float(((u32)bin << 16) | (u32)low);
    }
}

__global__ void edges_kernel(const float* __restrict__ vals, double* __restrict__ edges) {
    if (threadIdx.x == 0 && blockIdx.x == 0) {
        double step = (double)NROWS / 15.0;
        for (int k = 0; k < 16; ++k) {
            double e;
            if (k == 0)       e = (double)vals[0];
            else if (k == 15) e = (double)vals[30];
            else {
                long long ik = ((long long)k * 100000) / 3;
                double frac = (double)k * step - (double)ik;
                double a = (double)vals[2 * k];
                double b = (double)vals[2 * k + 1];
                e = a + frac * (b - a);
            }
            edges[k] = e;
        }
    }
}

// bin = (#edges strictly < conf) - 1; valid if in [0,14].
__global__ __launch_bounds__(256) void bin_accum_kernel(
    const float* __restrict__ conf_s, const float* __restrict__ wper,
    const float* __restrict__ conf_t, const double* __restrict__ edges,
    float* __restrict__ g_wnum, int* __restrict__ g_cnt)
{
    __shared__ float l_w[NBINS];
    __shared__ int   l_c[NBINS];
    int t = threadIdx.x;
    if (t < NBINS) { l_w[t] = 0.0f; l_c[t] = 0; }
    __syncthreads();
    double e[16];
    #pragma unroll
    for (int j = 0; j < 16; ++j) e[j] = edges[j];
    int i = blockIdx.x * 256 + t;
    if (i < NROWS) {
        double c = (double)conf_s[i];
        int cnt = 0;
        #pragma unroll
        for (int j = 0; j < 16; ++j) cnt += (c > e[j]) ? 1 : 0;
        if (cnt >= 1 && cnt <= NBINS) {
            float w = wper[i];
            if (w != 0.0f) atomicAdd(&l_w[cnt - 1], w);
        }
    } else if (i < 2 * NROWS) {
        double c = (double)conf_t[i - NROWS];
        int cnt = 0;
        #pragma unroll
        for (int j = 0; j < 16; ++j) cnt += (c > e[j]) ? 1 : 0;
        if (cnt >= 1 && cnt <= NBINS) atomicAdd(&l_c[cnt - 1], 1);
    }
    __syncthreads();
    if (t < NBINS) {
        float w = l_w[t];
        int cc = l_c[t];
        if (w != 0.0f) atomicAdd(&g_wnum[t], w);
        if (cc) atomicAdd(&g_cnt[t], cc);
    }
}

__global__ void cond_kernel(const float* __restrict__ g_wnum, const int* __restrict__ g_cnt,
                            double* __restrict__ ce)
{
    int t = threadIdx.x;
    if (t < NBINS) {
        int d = g_cnt[t] - 1; if (d < 1) d = 1;
        ce[t] = ((double)(NROWS - 1) / (double)NROWS) * (double)g_wnum[t] / (double)d;
    }
}

__global__ __launch_bounds__(256) void diff_kernel(
    const float* __restrict__ conf_t, const double* __restrict__ edges,
    const double* __restrict__ ce, float* __restrict__ g_perbin)
{
    __shared__ float l_p[NBINS];
    int t = threadIdx.x;
    if (t < NBINS) l_p[t] = 0.0f;
    __syncthreads();
    double e[16];
    #pragma unroll
    for (int j = 0; j < 16; ++j) e[j] = edges[j];
    int i = blockIdx.x * 256 + t;
    if (i < NROWS) {
        double c = (double)conf_t[i];
        int cnt = 0;
        #pragma unroll
        for (int j = 0; j < 16; ++j) cnt += (c > e[j]) ? 1 : 0;
        if (cnt >= 1 && cnt <= NBINS) {
            double d = c - ce[cnt - 1];
            atomicAdd(&l_p[cnt - 1], (float)(d * d));
        }
    }
    __syncthreads();
    if (t < NBINS) {
        float p = l_p[t];
        if (p != 0.0f) atomicAdd(&g_perbin[t], p);
    }
}

__global__ void final_kernel(const float* __restrict__ g_perbin, const int* __restrict__ g_cnt,
                             float* __restrict__ out)
{
    if (threadIdx.x == 0 && blockIdx.x == 0) {
        double ssum = 0.0;
        for (int b = 0; b < NBINS; ++b)
            if (g_cnt[b] > 1) ssum += (double)g_perbin[b];
        out[0] = (float)(ssum / (double)NROWS);
    }
}

extern "C" void kernel_launch(void* const* d_in, const int* in_sizes, int n_in,
                              void* d_out, int out_size, void* d_ws, size_t ws_size,
                              hipStream_t stream)
{
    const float* logits_s = (const float*)d_in[0];
    const int*   labels   = (const int*)d_in[1];
    const float* logits_t = (const float*)d_in[2];
    const float* weight   = (const float*)d_in[3];

    char* ws = (char*)d_ws;
    float*  conf_t   = (float*)(ws + OFF_CONF_T);
    float*  conf_s   = (float*)(ws + OFF_CONF_S);
    float*  wper     = (float*)(ws + OFF_WPER);
    u32*    chist    = (u32*)(ws + OFF_CHIST);
    u32*    shist    = (u32*)(ws + OFF_SHIST);
    int*    smap     = (int*)(ws + OFF_SMAP);
    int*    meta     = (int*)(ws + OFF_META);
    float*  vals     = (float*)(ws + OFF_VALS);
    double* edges    = (double*)(ws + OFF_EDGES);
    double* ce       = (double*)(ws + OFF_CE);
    float*  g_wnum   = (float*)(ws + OFF_ACC);
    int*    g_cnt    = (int*)(ws + OFF_ACC + 64);
    float*  g_perbin = (float*)(ws + OFF_ACC + 128);
    float*  out      = (float*)d_out;

    int zwords = (OFF_ZEND - OFF_CHIST) / 4;
    zero_kernel<<<(zwords + 255) / 256, 256, 0, stream>>>((u32*)(ws + OFF_CHIST), zwords);

    int tb = (NROWS + TROWS - 1) / TROWS;      // 7813 tiles of 64 rows
    int gb = (NROWS + 255) / 256;
    conf_kernel<<<2 * tb, 256, 0, stream>>>(logits_t, logits_s, labels, weight,
                                            conf_t, conf_s, wper, tb);
    hist_kernel<<<HISTB, 256, 0, stream>>>(conf_t, chist);
    rank_prep_kernel<<<1, 1024, 0, stream>>>(chist, smap, meta);
    slot_hist_kernel<<<gb, 256, 0, stream>>>(conf_t, smap, shist);
    select_kernel<<<NRANK, 1024, 0, stream>>>(shist, meta, vals);
    edges_kernel<<<1, 64, 0, stream>>>(vals, edges);
    bin_accum_kernel<<<(2 * NROWS + 255) / 256, 256, 0, stream>>>(conf_s, wper, conf_t, edges, g_wnum, g_cnt);
    cond_kernel<<<1, 64, 0, stream>>>(g_wnum, g_cnt, ce);
    diff_kernel<<<gb, 256, 0, stream>>>(conf_t, edges, ce, g_perbin);
    final_kernel<<<1, 64, 0, stream>>>(g_perbin, g_cnt, out);
}